// Round 1
// baseline (304.618 us; speedup 1.0000x reference)
//
#include <hip/hip_runtime.h>

#define NCH 30

__device__ __forceinline__ float iou_fn(float x1, float y1, float w1, float h1,
                                        float x2, float y2, float w2, float h2) {
    float a1 = w1 * h1, a2 = w2 * h2;
    float left  = fmaxf(x1 - w1 * 0.5f, x2 - w2 * 0.5f);
    float right = fminf(x1 + w1 * 0.5f, x2 + w2 * 0.5f);
    float top   = fmaxf(y1 - h1 * 0.5f, y2 - h2 * 0.5f);
    float bot   = fminf(y1 + h1 * 0.5f, y2 + h2 * 0.5f);
    float iw = fmaxf(right - left, 0.0f);
    float ih = fmaxf(bot - top, 0.0f);
    float inter = iw * ih;
    float uni = a1 + a2 - inter;
    return (inter > 0.0f) ? (inter / uni) : 0.0f;
}

__global__ void zero_ws_kernel(double* ws) {
    if (threadIdx.x < 4) ws[threadIdx.x] = 0.0;
}

__global__ __launch_bounds__(256) void yolo_loss_kernel(
        const float* __restrict__ pred, const float* __restrict__ targ,
        double* __restrict__ ws, int n_cells) {
    int cell = blockIdx.x * 256 + threadIdx.x;

    float coord = 0.0f, lobj = 0.0f, lnoobj = 0.0f, lclass = 0.0f;

    if (cell < n_cells) {
        float p[NCH], t[NCH];
        const float2* pp = reinterpret_cast<const float2*>(pred) + (size_t)cell * (NCH / 2);
        const float2* tp = reinterpret_cast<const float2*>(targ) + (size_t)cell * (NCH / 2);
#pragma unroll
        for (int i = 0; i < NCH / 2; i++) { float2 v = pp[i]; p[2 * i] = v.x; p[2 * i + 1] = v.y; }
#pragma unroll
        for (int i = 0; i < NCH / 2; i++) { float2 v = tp[i]; t[2 * i] = v.x; t[2 * i + 1] = v.y; }

        float obj_f = (t[0] == 1.0f) ? 1.0f : 0.0f;

        float iou1 = iou_fn(p[1], p[2], p[3], p[4], t[1], t[2], t[3], t[4]);
        float iou2 = iou_fn(t[6], t[7], t[8], t[9], t[1], t[2], t[3], t[4]);
        bool r = iou1 > iou2;

        float px = r ? p[1] : p[6], py = r ? p[2] : p[7];
        float pw = r ? p[3] : p[8], ph = r ? p[4] : p[9];
        float tx = r ? t[1] : t[6], ty = r ? t[2] : t[7];
        float tw = r ? t[3] : t[8], th = r ? t[4] : t[9];

        float dx = px - tx, dy = py - ty;
        float cell_xy = dx * dx + dy * dy;
        float sw = sqrtf(pw) - sqrtf(tw), sh = sqrtf(ph) - sqrtf(th);
        float cell_wh = sw * sw + sh * sh;

        float conf_resp  = r ? p[0] : p[5];
        float iou_resp   = r ? iou1 : iou2;
        float conf_other = r ? p[5] : p[0];
        float d = conf_resp - iou_resp;

        coord  = obj_f * (cell_xy + cell_wh);
        lobj   = obj_f * d * d;
        lnoobj = obj_f * conf_other * conf_other
               + (1.0f - obj_f) * (p[0] * p[0] + p[5] * p[5]);

        float cls = 0.0f;
#pragma unroll
        for (int i = 10; i < NCH; i++) { float e = p[i] - t[i]; cls += e * e; }
        lclass = obj_f * cls;
    }

    // wave-64 shuffle reduction
#pragma unroll
    for (int off = 32; off > 0; off >>= 1) {
        coord  += __shfl_down(coord, off);
        lobj   += __shfl_down(lobj, off);
        lnoobj += __shfl_down(lnoobj, off);
        lclass += __shfl_down(lclass, off);
    }

    __shared__ float red[4][4];
    int lane = threadIdx.x & 63;
    int wid  = threadIdx.x >> 6;
    if (lane == 0) {
        red[wid][0] = coord; red[wid][1] = lobj;
        red[wid][2] = lnoobj; red[wid][3] = lclass;
    }
    __syncthreads();
    if (threadIdx.x == 0) {
        double s0 = 0.0, s1 = 0.0, s2 = 0.0, s3 = 0.0;
        for (int w = 0; w < 4; w++) {
            s0 += (double)red[w][0];
            s1 += (double)red[w][1];
            s2 += (double)red[w][2];
            s3 += (double)red[w][3];
        }
        atomicAdd(ws + 0, s0);
        atomicAdd(ws + 1, s1);
        atomicAdd(ws + 2, s2);
        atomicAdd(ws + 3, s3);
    }
}

__global__ void finalize_kernel(const double* __restrict__ ws, float* __restrict__ out,
                                double inv_bs) {
    if (threadIdx.x == 0) {
        double c  = ws[0] * 5.0 * inv_bs;   // LAMBDA_COORD
        double o  = ws[1] * inv_bs;
        double n  = ws[2] * 0.5 * inv_bs;   // LAMBDA_NOOBJ
        double cl = ws[3] * inv_bs;
        out[0] = (float)c;
        out[1] = (float)o;
        out[2] = (float)n;
        out[3] = (float)cl;
        out[4] = (float)(c + o + n + cl);
    }
}

extern "C" void kernel_launch(void* const* d_in, const int* in_sizes, int n_in,
                              void* d_out, int out_size, void* d_ws, size_t ws_size,
                              hipStream_t stream) {
    const float* pred = (const float*)d_in[0];
    const float* targ = (const float*)d_in[1];
    float* out = (float*)d_out;
    double* ws = (double*)d_ws;

    int n_cells = in_sizes[0] / NCH;          // batch * 7 * 7
    int batch   = n_cells / 49;

    zero_ws_kernel<<<1, 64, 0, stream>>>(ws);

    int blocks = (n_cells + 255) / 256;
    yolo_loss_kernel<<<blocks, 256, 0, stream>>>(pred, targ, ws, n_cells);

    finalize_kernel<<<1, 64, 0, stream>>>(ws, out, 1.0 / (double)batch);
}

// Round 2
// 205.501 us; speedup vs baseline: 1.4823x; 1.4823x over previous
//
#include <hip/hip_runtime.h>

#define NCH 30
#define CPB 128              // cells per chunk
#define THREADS 256
#define GRID 1280            // 5 blocks/CU * 256 CUs (LDS-capped at 5 resident)

__device__ __forceinline__ float iou_fn(float x1, float y1, float w1, float h1,
                                        float x2, float y2, float w2, float h2) {
    float a1 = w1 * h1, a2 = w2 * h2;
    float left  = fmaxf(x1 - w1 * 0.5f, x2 - w2 * 0.5f);
    float right = fminf(x1 + w1 * 0.5f, x2 + w2 * 0.5f);
    float top   = fmaxf(y1 - h1 * 0.5f, y2 - h2 * 0.5f);
    float bot   = fminf(y1 + h1 * 0.5f, y2 + h2 * 0.5f);
    float iw = fmaxf(right - left, 0.0f);
    float ih = fmaxf(bot - top, 0.0f);
    float inter = iw * ih;
    float uni = a1 + a2 - inter;
    return (inter > 0.0f) ? (inter / uni) : 0.0f;
}

__global__ __launch_bounds__(THREADS) void yolo_main(
        const float* __restrict__ pred, const float* __restrict__ targ,
        float4* __restrict__ partials, int n_cells) {
    __shared__ float sp[CPB * NCH];   // 15360 B
    __shared__ float st[CPB * NCH];   // 15360 B

    const int tid = threadIdx.x;
    const int nchunks = (n_cells + CPB - 1) / CPB;
    const long long total_floats = (long long)n_cells * NCH;

    float coord = 0.f, lobj = 0.f, lnoobj = 0.f, lclass = 0.f;

    for (int c = blockIdx.x; c < nchunks; c += gridDim.x) {
        const long long base = (long long)c * (CPB * NCH);
        const long long rem = total_floats - base;
        const int nflt = rem < (long long)(CPB * NCH) ? (int)rem : (CPB * NCH);
        const int n4 = nflt >> 2;

        const float4* p4 = reinterpret_cast<const float4*>(pred + base);
        const float4* t4 = reinterpret_cast<const float4*>(targ + base);
        float4* sp4 = reinterpret_cast<float4*>(sp);
        float4* st4 = reinterpret_cast<float4*>(st);
        for (int i = tid; i < n4; i += THREADS) {
            float4 a = p4[i];
            float4 b = t4[i];
            sp4[i] = a;
            st4[i] = b;
        }
        for (int i = (n4 << 2) + tid; i < nflt; i += THREADS) {   // scalar tail
            sp[i] = pred[base + i];
            st[i] = targ[base + i];
        }
        __syncthreads();

        if (tid < CPB) {
            long long cell = (long long)c * CPB + tid;
            if (cell < n_cells) {
                const float* p = sp + tid * NCH;
                const float* t = st + tid * NCH;

                float obj_f = (t[0] == 1.0f) ? 1.0f : 0.0f;

                float iou1 = iou_fn(p[1], p[2], p[3], p[4], t[1], t[2], t[3], t[4]);
                float iou2 = iou_fn(t[6], t[7], t[8], t[9], t[1], t[2], t[3], t[4]);
                bool r = iou1 > iou2;

                float px = r ? p[1] : p[6], py = r ? p[2] : p[7];
                float pw = r ? p[3] : p[8], ph = r ? p[4] : p[9];
                float tx = r ? t[1] : t[6], ty = r ? t[2] : t[7];
                float tw = r ? t[3] : t[8], th = r ? t[4] : t[9];

                float dx = px - tx, dy = py - ty;
                float cxy = dx * dx + dy * dy;
                float swv = sqrtf(pw) - sqrtf(tw), shv = sqrtf(ph) - sqrtf(th);
                float cwh = swv * swv + shv * shv;

                float conf_resp  = r ? p[0] : p[5];
                float iou_resp   = r ? iou1 : iou2;
                float conf_other = r ? p[5] : p[0];
                float dconf = conf_resp - iou_resp;

                coord  += obj_f * (cxy + cwh);
                lobj   += obj_f * dconf * dconf;
                lnoobj += obj_f * conf_other * conf_other
                        + (1.0f - obj_f) * (p[0] * p[0] + p[5] * p[5]);

                float cls = 0.0f;
#pragma unroll
                for (int i = 10; i < NCH; i++) { float e = p[i] - t[i]; cls += e * e; }
                lclass += obj_f * cls;
            }
        }
        __syncthreads();
    }

    // wave-64 shuffle reduction
#pragma unroll
    for (int off = 32; off > 0; off >>= 1) {
        coord  += __shfl_down(coord, off);
        lobj   += __shfl_down(lobj, off);
        lnoobj += __shfl_down(lnoobj, off);
        lclass += __shfl_down(lclass, off);
    }

    __shared__ float red[4][4];
    int lane = tid & 63;
    int wid  = tid >> 6;
    if (lane == 0) {
        red[wid][0] = coord; red[wid][1] = lobj;
        red[wid][2] = lnoobj; red[wid][3] = lclass;
    }
    __syncthreads();
    if (tid == 0) {
        float s0 = 0.f, s1 = 0.f, s2 = 0.f, s3 = 0.f;
        for (int w = 0; w < 4; w++) {
            s0 += red[w][0]; s1 += red[w][1];
            s2 += red[w][2]; s3 += red[w][3];
        }
        partials[blockIdx.x] = make_float4(s0, s1, s2, s3);
    }
}

__global__ __launch_bounds__(THREADS) void yolo_reduce(
        const float4* __restrict__ partials, int nparts,
        float* __restrict__ out, double inv_bs) {
    double s0 = 0.0, s1 = 0.0, s2 = 0.0, s3 = 0.0;
    for (int i = threadIdx.x; i < nparts; i += THREADS) {
        float4 v = partials[i];
        s0 += (double)v.x; s1 += (double)v.y;
        s2 += (double)v.z; s3 += (double)v.w;
    }
#pragma unroll
    for (int off = 32; off > 0; off >>= 1) {
        s0 += __shfl_down(s0, off);
        s1 += __shfl_down(s1, off);
        s2 += __shfl_down(s2, off);
        s3 += __shfl_down(s3, off);
    }
    __shared__ double red[4][4];
    int lane = threadIdx.x & 63;
    int wid  = threadIdx.x >> 6;
    if (lane == 0) {
        red[wid][0] = s0; red[wid][1] = s1;
        red[wid][2] = s2; red[wid][3] = s3;
    }
    __syncthreads();
    if (threadIdx.x == 0) {
        double a0 = 0, a1 = 0, a2 = 0, a3 = 0;
        for (int w = 0; w < 4; w++) {
            a0 += red[w][0]; a1 += red[w][1];
            a2 += red[w][2]; a3 += red[w][3];
        }
        double c  = a0 * 5.0 * inv_bs;   // LAMBDA_COORD
        double o  = a1 * inv_bs;
        double n  = a2 * 0.5 * inv_bs;   // LAMBDA_NOOBJ
        double cl = a3 * inv_bs;
        out[0] = (float)c;
        out[1] = (float)o;
        out[2] = (float)n;
        out[3] = (float)cl;
        out[4] = (float)(c + o + n + cl);
    }
}

extern "C" void kernel_launch(void* const* d_in, const int* in_sizes, int n_in,
                              void* d_out, int out_size, void* d_ws, size_t ws_size,
                              hipStream_t stream) {
    const float* pred = (const float*)d_in[0];
    const float* targ = (const float*)d_in[1];
    float* out = (float*)d_out;
    float4* partials = (float4*)d_ws;

    int n_cells = in_sizes[0] / NCH;          // batch * 7 * 7
    int batch   = n_cells / 49;
    int nchunks = (n_cells + CPB - 1) / CPB;
    int grid    = nchunks < GRID ? nchunks : GRID;

    yolo_main<<<grid, THREADS, 0, stream>>>(pred, targ, partials, n_cells);
    yolo_reduce<<<1, THREADS, 0, stream>>>(partials, grid, out, 1.0 / (double)batch);
}